// Round 1
// baseline (2594.454 us; speedup 1.0000x reference)
//
#include <hip/hip_runtime.h>
#include <math.h>

#define BT      65536
#define HID     512
#define ACT     64
#define SRC     2
#define AGE     16
#define IN_DIM  594
#define TRUNK   256
#define BINS    20
#define PHASES  7
#define ROWS    16
#define XS_STRIDE 596   // floats; 596*4 B is 16B-aligned per row
#define ZS_STRIDE 260   // pad 256->260 to break bank aliasing across rows
#define NCOMBO  320     // 2 heads * 20 bins * (1 base + 7 experts)

// ---------------------------------------------------------------------------
// Pack all head weights into Wall[320][256] (combo-major, d-minor) + bias[320]
// combo c: h = c/160 (0=inst,1=group); k = (c%160)/8; p = c%8 (0=base, 1..7=expert p-1)
// ---------------------------------------------------------------------------
__global__ void pack_weights(const float* __restrict__ inst_base_w,
                             const float* __restrict__ inst_base_b,
                             const float* __restrict__ group_base_w,
                             const float* __restrict__ group_base_b,
                             const float* __restrict__ inst_exp_w,
                             const float* __restrict__ inst_exp_b,
                             const float* __restrict__ group_exp_w,
                             const float* __restrict__ group_exp_b,
                             float* __restrict__ wall,
                             float* __restrict__ wbias) {
    int c = blockIdx.x;
    int d = threadIdx.x;
    int h   = c / 160;
    int rem = c - h * 160;
    int k   = rem >> 3;
    int p   = rem & 7;
    const float* bw = h ? group_base_w : inst_base_w;
    const float* ew = h ? group_exp_w  : inst_exp_w;
    float v;
    if (p == 0) v = bw[d * BINS + k];
    else        v = ew[((p - 1) * TRUNK + d) * BINS + k];
    wall[c * TRUNK + d] = v;
    if (d == 0) {
        const float* bb = h ? group_base_b : inst_base_b;
        const float* eb = h ? group_exp_b  : inst_exp_b;
        wbias[c] = (p == 0) ? bb[k] : eb[(p - 1) * BINS + k];
    }
}

// ---------------------------------------------------------------------------
// Fused main kernel: 16 tokens per 256-thread block.
// LDS: xs[16][596] union { zs[16][260] ; e[16][320] }  (38144 B) + small pw.
// ---------------------------------------------------------------------------
__global__ __launch_bounds__(256) void fused_main(
    const float* __restrict__ h_t, const float* __restrict__ a_t,
    const float* __restrict__ d_t, const float* __restrict__ age,
    const float* __restrict__ trunk_w, const float* __restrict__ trunk_b,
    const float* __restrict__ router_w, const float* __restrict__ router_b,
    const float* __restrict__ wall, const float* __restrict__ wbias,
    float* __restrict__ out) {

    __shared__ float smem[ROWS * XS_STRIDE];   // xs, later reused as zs + e
    __shared__ float logits[ROWS][8];
    __shared__ float pw[ROWS][8];

    const int tid    = threadIdx.x;
    const int block0 = blockIdx.x * ROWS;      // first token of this block

    // ---- phase 1: stage x = concat(h, a, d, age) into LDS -----------------
    for (int idx = tid; idx < ROWS * IN_DIM; idx += 256) {
        int r = idx / IN_DIM;
        int c = idx - r * IN_DIM;
        int t = block0 + r;
        float v;
        if (c < HID)                   v = h_t[t * HID + c];
        else if (c < HID + ACT)        v = a_t[t * ACT + (c - HID)];
        else if (c < HID + ACT + SRC)  v = d_t[t * SRC + (c - HID - ACT)];
        else                           v = age[t * AGE + (c - HID - ACT - SRC)];
        smem[r * XS_STRIDE + c] = v;
    }
    __syncthreads();

    // ---- phase 2: router logits + softmax ---------------------------------
    if (tid < ROWS * PHASES) {
        int r = tid / PHASES, p = tid - r * PHASES;
        float acc = router_b[p];
        const float* xr = &smem[r * XS_STRIDE];
        for (int k = 0; k < HID; ++k)
            acc = fmaf(xr[k], router_w[k * PHASES + p], acc);
        logits[r][p] = acc;
    }
    __syncthreads();
    if (tid < ROWS) {
        float m = logits[tid][0];
        #pragma unroll
        for (int p = 1; p < PHASES; ++p) m = fmaxf(m, logits[tid][p]);
        float e[PHASES]; float s = 0.f;
        #pragma unroll
        for (int p = 0; p < PHASES; ++p) { e[p] = expf(logits[tid][p] - m); s += e[p]; }
        float inv = 1.f / s;
        #pragma unroll
        for (int p = 0; p < PHASES; ++p) pw[tid][p] = e[p] * inv;
    }
    // (pw reads happen after later barriers; no barrier needed here)

    // ---- phase 3: trunk GEMM, 4 rows x 4 cols per thread ------------------
    const int tx = tid & 63;   // cols tx*4 .. tx*4+3
    const int ty = tid >> 6;   // rows ty*4 .. ty*4+3
    float acc[4][4] = {{0.f}};
    const float* xbase = &smem[(ty * 4) * XS_STRIDE];

    int k = 0;
    for (; k + 4 <= IN_DIM; k += 4) {
        float4 w0 = *reinterpret_cast<const float4*>(&trunk_w[(k + 0) * TRUNK + tx * 4]);
        float4 w1 = *reinterpret_cast<const float4*>(&trunk_w[(k + 1) * TRUNK + tx * 4]);
        float4 w2 = *reinterpret_cast<const float4*>(&trunk_w[(k + 2) * TRUNK + tx * 4]);
        float4 w3 = *reinterpret_cast<const float4*>(&trunk_w[(k + 3) * TRUNK + tx * 4]);
        #pragma unroll
        for (int i = 0; i < 4; ++i) {
            float4 xv = *reinterpret_cast<const float4*>(&xbase[i * XS_STRIDE + k]);
            acc[i][0] = fmaf(xv.x, w0.x, fmaf(xv.y, w1.x, fmaf(xv.z, w2.x, fmaf(xv.w, w3.x, acc[i][0]))));
            acc[i][1] = fmaf(xv.x, w0.y, fmaf(xv.y, w1.y, fmaf(xv.z, w2.y, fmaf(xv.w, w3.y, acc[i][1]))));
            acc[i][2] = fmaf(xv.x, w0.z, fmaf(xv.y, w1.z, fmaf(xv.z, w2.z, fmaf(xv.w, w3.z, acc[i][2]))));
            acc[i][3] = fmaf(xv.x, w0.w, fmaf(xv.y, w1.w, fmaf(xv.z, w2.w, fmaf(xv.w, w3.w, acc[i][3]))));
        }
    }
    for (; k < IN_DIM; ++k) {   // tail: k = 592, 593
        float4 w0 = *reinterpret_cast<const float4*>(&trunk_w[k * TRUNK + tx * 4]);
        #pragma unroll
        for (int i = 0; i < 4; ++i) {
            float xv = xbase[i * XS_STRIDE + k];
            acc[i][0] = fmaf(xv, w0.x, acc[i][0]);
            acc[i][1] = fmaf(xv, w0.y, acc[i][1]);
            acc[i][2] = fmaf(xv, w0.z, acc[i][2]);
            acc[i][3] = fmaf(xv, w0.w, acc[i][3]);
        }
    }

    float4 bv = *reinterpret_cast<const float4*>(&trunk_b[tx * 4]);
    __syncthreads();   // all xs reads (trunk + router) complete before overwrite

    // bias + exact GELU, store z into reused LDS (stride 260)
    {
        const float kInvSqrt2 = 0.70710678118654752f;
        #pragma unroll
        for (int i = 0; i < 4; ++i) {
            float v0 = acc[i][0] + bv.x;
            float v1 = acc[i][1] + bv.y;
            float v2 = acc[i][2] + bv.z;
            float v3 = acc[i][3] + bv.w;
            v0 = 0.5f * v0 * (1.f + erff(v0 * kInvSqrt2));
            v1 = 0.5f * v1 * (1.f + erff(v1 * kInvSqrt2));
            v2 = 0.5f * v2 * (1.f + erff(v2 * kInvSqrt2));
            v3 = 0.5f * v3 * (1.f + erff(v3 * kInvSqrt2));
            float* zrow = &smem[(ty * 4 + i) * ZS_STRIDE + tx * 4];
            zrow[0] = v0; zrow[1] = v1; zrow[2] = v2; zrow[3] = v3;
        }
    }
    __syncthreads();

    // ---- phase 4: head dots. thread -> row r = tid>>4, 20 combos ----------
    {
        const int r  = tid >> 4;
        const int li = tid & 15;
        const float* zrow = &smem[r * ZS_STRIDE];
        float* ebuf = &smem[ROWS * ZS_STRIDE];   // e[16][320] at float offset 4160
        float eacc[20];
        #pragma unroll
        for (int j = 0; j < 20; ++j) eacc[j] = wbias[li * 20 + j];

        for (int db = 0; db < TRUNK; db += 32) {
            float4 zv[8];
            #pragma unroll
            for (int q = 0; q < 8; ++q)
                zv[q] = *reinterpret_cast<const float4*>(&zrow[db + q * 4]);
            #pragma unroll
            for (int j = 0; j < 20; ++j) {
                const float* wrow = &wall[(li * 20 + j) * TRUNK + db];
                #pragma unroll
                for (int q = 0; q < 8; ++q) {
                    float4 wv = *reinterpret_cast<const float4*>(&wrow[q * 4]);
                    eacc[j] = fmaf(zv[q].x, wv.x, eacc[j]);
                    eacc[j] = fmaf(zv[q].y, wv.y, eacc[j]);
                    eacc[j] = fmaf(zv[q].z, wv.z, eacc[j]);
                    eacc[j] = fmaf(zv[q].w, wv.w, eacc[j]);
                }
            }
        }
        #pragma unroll
        for (int j = 0; j < 20; ++j)
            ebuf[r * NCOMBO + li * 20 + j] = eacc[j];
    }
    __syncthreads();

    // ---- phase 5: weighted phase reduction + store ------------------------
    {
        const float* ebuf = &smem[ROWS * ZS_STRIDE];
        for (int idx = tid; idx < ROWS * 40; idx += 256) {
            int r   = idx / 40;
            int rem = idx - r * 40;
            int h   = rem / 20;
            int kb  = rem - h * 20;
            const float* ep = &ebuf[r * NCOMBO + h * 160 + kb * 8];
            float v = ep[0];
            #pragma unroll
            for (int p = 1; p < 8; ++p) v = fmaf(pw[r][p - 1], ep[p], v);
            int t = block0 + r;
            out[h * (BT * BINS) + t * BINS + kb] = v;
        }
    }
}

// ---------------------------------------------------------------------------
extern "C" void kernel_launch(void* const* d_in, const int* in_sizes, int n_in,
                              void* d_out, int out_size, void* d_ws, size_t ws_size,
                              hipStream_t stream) {
    const float* h_t          = (const float*)d_in[0];
    const float* a_t          = (const float*)d_in[1];
    const float* d_t          = (const float*)d_in[2];
    const float* age_embed    = (const float*)d_in[3];
    const float* trunk_w      = (const float*)d_in[4];
    const float* trunk_b      = (const float*)d_in[5];
    const float* inst_base_w  = (const float*)d_in[6];
    const float* inst_base_b  = (const float*)d_in[7];
    const float* group_base_w = (const float*)d_in[8];
    const float* group_base_b = (const float*)d_in[9];
    const float* inst_exp_w   = (const float*)d_in[10];
    const float* inst_exp_b   = (const float*)d_in[11];
    const float* group_exp_w  = (const float*)d_in[12];
    const float* group_exp_b  = (const float*)d_in[13];
    const float* router_w     = (const float*)d_in[14];
    const float* router_b     = (const float*)d_in[15];

    float* wall  = (float*)d_ws;                 // [320][256]
    float* wbias = wall + NCOMBO * TRUNK;        // [320]

    pack_weights<<<NCOMBO, 256, 0, stream>>>(
        inst_base_w, inst_base_b, group_base_w, group_base_b,
        inst_exp_w, inst_exp_b, group_exp_w, group_exp_b, wall, wbias);

    fused_main<<<BT / ROWS, 256, 0, stream>>>(
        h_t, a_t, d_t, age_embed, trunk_w, trunk_b,
        router_w, router_b, wall, wbias, (float*)d_out);
}

// Round 2
// 108.326 us; speedup vs baseline: 23.9505x; 23.9505x over previous
//
#include <hip/hip_runtime.h>
#include <math.h>

typedef unsigned int uint;
typedef unsigned short ushort;

using short8 = __attribute__((ext_vector_type(8))) short;
using f32x4  = __attribute__((ext_vector_type(4))) float;

#define BT      65536
#define HID     512
#define IN_DIM  594
#define TRUNK   256
#define BINS    20
#define NKCH    19      // ceil(608/32): K chunks of 32 for trunk (594 padded to 608)
#define NCOMBO  320

// ws layout (ushort units unless noted)
#define WT_P_SZ (19*16*64*8)   // 155648 bf16 : trunk W, B-frag layout
#define RP_SZ   (16*64*8)      //   8192 bf16 : router W
#define WA_P_SZ (8*20*64*8)    //  81920 bf16 : packed head W (320 combos)

__device__ inline ushort f2bf(float f) {
    uint u = __float_as_uint(f);
    return (ushort)((u + 0x7fffu + ((u >> 16) & 1u)) >> 16);   // RNE, inputs are finite
}

// ---------------------------------------------------------------------------
// Pack everything to bf16 in MFMA B-fragment layout:
//   frag element j of lane l of frag (kk,n):  B[k][col], k = kk*32 + (l>>4)*8 + j,
//   col = n*16 + (l&15); stored at ((kk*NF+n)*64 + l)*8 + j  (16B/lane, coalesced)
// ---------------------------------------------------------------------------
__global__ __launch_bounds__(64) void pack_all(
    const float* __restrict__ trunk_w, const float* __restrict__ router_w,
    const float* __restrict__ inst_base_w, const float* __restrict__ inst_base_b,
    const float* __restrict__ group_base_w, const float* __restrict__ group_base_b,
    const float* __restrict__ inst_exp_w, const float* __restrict__ inst_exp_b,
    const float* __restrict__ group_exp_w, const float* __restrict__ group_exp_b,
    ushort* __restrict__ WtP, ushort* __restrict__ RP,
    ushort* __restrict__ WaP, float* __restrict__ wbias)
{
    const int b = blockIdx.x, l = threadIdx.x;
    const int lr = l & 15, lg = l >> 4;
    if (b < 304) {                      // trunk: kk 0..18, n 0..15
        int kk = b >> 4, n = b & 15;
        int col = n * 16 + lr;
        ushort* dst = WtP + ((size_t)(kk * 16 + n) * 64 + l) * 8;
        #pragma unroll
        for (int j = 0; j < 8; ++j) {
            int k = kk * 32 + lg * 8 + j;
            dst[j] = (k < IN_DIM) ? f2bf(trunk_w[k * TRUNK + col]) : (ushort)0;
        }
    } else if (b < 320) {               // router: kk 0..15, single N-frag (7 valid cols)
        int kk = b - 304;
        ushort* dst = RP + ((size_t)(kk * 64 + l)) * 8;
        #pragma unroll
        for (int j = 0; j < 8; ++j) {
            int k = kk * 32 + lg * 8 + j;
            dst[j] = (lr < 7) ? f2bf(router_w[k * 7 + lr]) : (ushort)0;
        }
    } else if (b < 480) {               // heads: kk 0..7, n 0..19 (320 combos)
        int b2 = b - 320, kk = b2 / 20, n = b2 % 20;
        int combo = n * 16 + lr;        // = h*160 + kb*8 + p
        int h = combo / 160, rem = combo % 160, kb = rem >> 3, p = rem & 7;
        const float* bw = h ? group_base_w : inst_base_w;
        const float* ew = h ? group_exp_w  : inst_exp_w;
        ushort* dst = WaP + ((size_t)(kk * 20 + n) * 64 + l) * 8;
        #pragma unroll
        for (int j = 0; j < 8; ++j) {
            int k = kk * 32 + lg * 8 + j;
            float v = (p == 0) ? bw[k * BINS + kb]
                               : ew[((p - 1) * TRUNK + k) * BINS + kb];
            dst[j] = f2bf(v);
        }
    } else {                            // bias[320] fp32
        for (int c = l; c < NCOMBO; c += 64) {
            int h = c / 160, rem = c % 160, kb = rem >> 3, p = rem & 7;
            const float* bb = h ? group_base_b : inst_base_b;
            const float* eb = h ? group_exp_b  : inst_exp_b;
            wbias[c] = (p == 0) ? bb[kb] : eb[(p - 1) * BINS + kb];
        }
    }
}

// ---------------------------------------------------------------------------
// Fused main: 128 tokens/block, 256 threads (4 waves), wave w -> rows w*32..+31.
// LDS 64KB: xs[2][128][32] bf16 (16KB, double-buffered staging) unioned with
// zs[128][256] bf16 (64KB, XOR-swizzled: 16B slot index ^= row&7).
// ---------------------------------------------------------------------------
__global__ __launch_bounds__(256, 2) void fused_mfma(
    const float* __restrict__ h_t, const float* __restrict__ a_t,
    const float* __restrict__ d_t, const float* __restrict__ age,
    const float* __restrict__ trunk_b, const float* __restrict__ router_b,
    const ushort* __restrict__ WtP, const ushort* __restrict__ RP,
    const ushort* __restrict__ WaP, const float* __restrict__ wbias,
    float* __restrict__ out)
{
    __shared__ alignas(16) ushort smem[32768];   // 64 KB

    const int tid = threadIdx.x;
    const int l = tid & 63, w = tid >> 6;
    const int lr = l & 15, lg = l >> 4;
    const int block0 = blockIdx.x * 128;

    // staging mapping: thread -> (row, 16-col half of 32-col chunk)
    const int srow = tid >> 1;
    const int scb  = (tid & 1) * 16;
    const int stok = block0 + srow;

    f32x4 acc[2][16];
    f32x4 accr[2];
    #pragma unroll
    for (int m = 0; m < 2; ++m) {
        accr[m] = (f32x4){0.f, 0.f, 0.f, 0.f};
        #pragma unroll
        for (int n = 0; n < 16; ++n) acc[m][n] = (f32x4){0.f, 0.f, 0.f, 0.f};
    }

    // ---- staging helpers (x = concat(h,a,d,age,0-pad) as bf16 chunks) -----
    auto stage_load = [&](int kk, float4 ld[4]) {
        int c0 = kk * 32 + scb;
        if (kk < 16) {
            const float4* p = (const float4*)(h_t + (size_t)stok * HID + c0);
            ld[0] = p[0]; ld[1] = p[1]; ld[2] = p[2]; ld[3] = p[3];
        } else if (kk < 18) {
            const float4* p = (const float4*)(a_t + (size_t)stok * 64 + (c0 - 512));
            ld[0] = p[0]; ld[1] = p[1]; ld[2] = p[2]; ld[3] = p[3];
        } else {
            float* f = (float*)ld;
            #pragma unroll
            for (int j = 0; j < 16; ++j) {
                int c = c0 + j;
                float v;
                if (c < 578)        v = d_t[(size_t)stok * 2 + (c - 576)];
                else if (c < 594)   v = age[(size_t)stok * 16 + (c - 578)];
                else                v = 0.f;
                f[j] = v;
            }
        }
    };
    auto stage_write = [&](int buf, float4 ld[4]) {
        const float* f = (const float*)ld;
        short8 v0, v1;
        #pragma unroll
        for (int j = 0; j < 8; ++j) {
            v0[j] = (short)f2bf(f[j]);
            v1[j] = (short)f2bf(f[j + 8]);
        }
        ushort* dst = smem + buf * 4096 + srow * 32 + scb;
        *(short8*)dst = v0;
        *(short8*)(dst + 8) = v1;
    };

    // ---- phase A: trunk GEMM (K=608) + fused router GEMM (K=512) ----------
    {
        float4 ld[4];
        stage_load(0, ld);
        stage_write(0, ld);
        __syncthreads();
        int cur = 0;
        for (int kk = 0; kk < NKCH; ++kk) {
            float4 nld[4];
            if (kk < NKCH - 1) stage_load(kk + 1, nld);     // issue early (T14)

            const ushort* xa = smem + cur * 4096;
            short8 a0 = *(const short8*)(xa + (w * 32 + lr) * 32 + lg * 8);
            short8 a1 = *(const short8*)(xa + (w * 32 + 16 + lr) * 32 + lg * 8);

            if (kk < 16) {
                short8 rb = *(const short8*)(RP + ((size_t)(kk * 64 + l)) * 8);
                accr[0] = __builtin_amdgcn_mfma_f32_16x16x32_bf16(a0, rb, accr[0], 0, 0, 0);
                accr[1] = __builtin_amdgcn_mfma_f32_16x16x32_bf16(a1, rb, accr[1], 0, 0, 0);
            }
            const ushort* wp = WtP + (size_t)kk * 16 * 64 * 8;
            #pragma unroll
            for (int n = 0; n < 16; ++n) {
                short8 bq = *(const short8*)(wp + ((size_t)n * 64 + l) * 8);
                acc[0][n] = __builtin_amdgcn_mfma_f32_16x16x32_bf16(a0, bq, acc[0][n], 0, 0, 0);
                acc[1][n] = __builtin_amdgcn_mfma_f32_16x16x32_bf16(a1, bq, acc[1][n], 0, 0, 0);
            }
            if (kk < NKCH - 1) stage_write(cur ^ 1, nld);   // write late
            __syncthreads();
            cur ^= 1;
        }
    }

    // ---- router softmax, kept in registers --------------------------------
    // lane l holds logit for row = w*32 + m*16 + lg*4 + r, phase p = lr (p<7)
    float pwv[2][4];
    {
        const float rb_l = (lr < 7) ? router_b[lr] : 0.f;
        #pragma unroll
        for (int m = 0; m < 2; ++m)
        #pragma unroll
        for (int r = 0; r < 4; ++r) {
            float x = (lr < 7) ? (accr[m][r] + rb_l) : -3.0e38f;
            float mx = x;
            mx = fmaxf(mx, __shfl_xor(mx, 1));
            mx = fmaxf(mx, __shfl_xor(mx, 2));
            mx = fmaxf(mx, __shfl_xor(mx, 4));
            mx = fmaxf(mx, __shfl_xor(mx, 8));
            float e = expf(x - mx);          // pad lanes -> exp(-inf)=0
            float s = e;
            s += __shfl_xor(s, 1);
            s += __shfl_xor(s, 2);
            s += __shfl_xor(s, 4);
            s += __shfl_xor(s, 8);
            pwv[m][r] = e / s;
        }
    }

    // ---- epilogue B: bias + exact GELU -> bf16 zs (swizzled) --------------
    {
        float tb_[16];
        #pragma unroll
        for (int n = 0; n < 16; ++n) tb_[n] = trunk_b[n * 16 + lr];
        char* zb = (char*)smem;
        #pragma unroll
        for (int m = 0; m < 2; ++m)
        #pragma unroll
        for (int n = 0; n < 16; ++n)
        #pragma unroll
        for (int r = 0; r < 4; ++r) {
            float v = acc[m][n][r] + tb_[n];
            v = 0.5f * v * (1.f + erff(v * 0.70710678118654752f));
            int row  = w * 32 + m * 16 + lg * 4 + r;
            int col  = n * 16 + lr;
            int slot = (col >> 3) ^ (row & 7);
            *(ushort*)(zb + row * 512 + slot * 16 + (col & 7) * 2) = f2bf(v);
        }
    }
    __syncthreads();

    // ---- phase C: head GEMM [128 x 320], K=256, two halves of 10 N-frags --
    const char* zb = (const char*)smem;
    const int p8 = l & 7;
    const int csrc = (l & 48) | (p8 ? (p8 - 1) : 0);
    const int row0 = w * 32 + lr;
    const int row1 = row0 + 16;          // (row1&7)==(row0&7)
    #pragma unroll 1
    for (int hf = 0; hf < 2; ++hf) {
        f32x4 acc2[2][10];
        #pragma unroll
        for (int m = 0; m < 2; ++m)
        #pragma unroll
        for (int n = 0; n < 10; ++n) acc2[m][n] = (f32x4){0.f, 0.f, 0.f, 0.f};
        float wb_[10];
        #pragma unroll
        for (int n = 0; n < 10; ++n) wb_[n] = wbias[(hf * 10 + n) * 16 + lr];

        #pragma unroll
        for (int kk = 0; kk < 8; ++kk) {
            short8 a0 = *(const short8*)(zb + row0 * 512 + (((kk * 4 + lg) ^ (row0 & 7)) << 4));
            short8 a1 = *(const short8*)(zb + row1 * 512 + (((kk * 4 + lg) ^ (row1 & 7)) << 4));
            const ushort* wp = WaP + (size_t)(kk * 20 + hf * 10) * 64 * 8;
            #pragma unroll
            for (int n = 0; n < 10; ++n) {
                short8 bq = *(const short8*)(wp + ((size_t)n * 64 + l) * 8);
                acc2[0][n] = __builtin_amdgcn_mfma_f32_16x16x32_bf16(a0, bq, acc2[0][n], 0, 0, 0);
                acc2[1][n] = __builtin_amdgcn_mfma_f32_16x16x32_bf16(a1, bq, acc2[1][n], 0, 0, 0);
            }
        }

        // ---- phase E: bias, phase-weighted 8-lane reduce, store -----------
        #pragma unroll
        for (int m = 0; m < 2; ++m)
        #pragma unroll
        for (int n = 0; n < 10; ++n)
        #pragma unroll
        for (int r = 0; r < 4; ++r) {
            float e = acc2[m][n][r] + wb_[n];
            float c = __shfl(pwv[m][r], csrc);      // pw for p = (l&7)-1, same row
            float coef = p8 ? c : 1.0f;             // p==0 is the base head
            float val = coef * e;
            val += __shfl_xor(val, 1);
            val += __shfl_xor(val, 2);
            val += __shfl_xor(val, 4);
            if (p8 == 0) {
                int combo = (hf * 10 + n) * 16 + lr;
                int h = combo / 160, rem = combo % 160, kb = rem >> 3;
                int t = block0 + w * 32 + m * 16 + lg * 4 + r;
                out[(size_t)h * (BT * BINS) + (size_t)t * BINS + kb] = val;
            }
        }
    }
}

// ---------------------------------------------------------------------------
extern "C" void kernel_launch(void* const* d_in, const int* in_sizes, int n_in,
                              void* d_out, int out_size, void* d_ws, size_t ws_size,
                              hipStream_t stream) {
    const float* h_t          = (const float*)d_in[0];
    const float* a_t          = (const float*)d_in[1];
    const float* d_t          = (const float*)d_in[2];
    const float* age_embed    = (const float*)d_in[3];
    const float* trunk_w      = (const float*)d_in[4];
    const float* trunk_b      = (const float*)d_in[5];
    const float* inst_base_w  = (const float*)d_in[6];
    const float* inst_base_b  = (const float*)d_in[7];
    const float* group_base_w = (const float*)d_in[8];
    const float* group_base_b = (const float*)d_in[9];
    const float* inst_exp_w   = (const float*)d_in[10];
    const float* inst_exp_b   = (const float*)d_in[11];
    const float* group_exp_w  = (const float*)d_in[12];
    const float* group_exp_b  = (const float*)d_in[13];
    const float* router_w     = (const float*)d_in[14];
    const float* router_b     = (const float*)d_in[15];

    ushort* WtP  = (ushort*)d_ws;
    ushort* RP   = WtP + WT_P_SZ;
    ushort* WaP  = RP + RP_SZ;
    float*  wbias = (float*)(WaP + WA_P_SZ);

    pack_all<<<481, 64, 0, stream>>>(
        trunk_w, router_w,
        inst_base_w, inst_base_b, group_base_w, group_base_b,
        inst_exp_w, inst_exp_b, group_exp_w, group_exp_b,
        WtP, RP, WaP, wbias);

    fused_mfma<<<BT / 128, 256, 0, stream>>>(
        h_t, a_t, d_t, age_embed, trunk_b, router_b,
        WtP, RP, WaP, wbias, (float*)d_out);
}